// Round 12
// baseline (154.235 us; speedup 1.0000x reference)
//
#include <hip/hip_runtime.h>

#define BB 4
#define CIN 128
#define T3 384
#define HH 128
#define WW 128
#define NPIX 16384
#define QKV_ELE (BB*T3*NPIX)

// MFMA packed-image geometry
#define SEC 4160
#define KGP 1040
#define PLN 520
// B tile (k4, 64-wide)
#define KGPB 520
#define PLNB 260

typedef __attribute__((ext_vector_type(8))) short bf16x8;
typedef __attribute__((ext_vector_type(4))) float f32x4;

__device__ __forceinline__ unsigned splitpack(float x) {
  unsigned u = __float_as_uint(x);
  unsigned hb = (u + 0x7fffu + ((u >> 16) & 1u)) >> 16;
  float lo = x - __uint_as_float(hb << 16);
  unsigned ul = __float_as_uint(lo);
  unsigned lb = (ul + 0x7fffu + ((ul >> 16) & 1u)) >> 16;
  return (hb << 16) | (lb & 0xffffu);
}

__device__ __forceinline__ void packpair(float a, float b, unsigned& hi, unsigned& lo) {
  unsigned p0 = splitpack(a), p1 = splitpack(b);
  hi = (p1 & 0xffff0000u) | (p0 >> 16);
  lo = (p1 << 16) | (p0 & 0xffffu);
}

// ============================================================================
// K0: pre-pack wqkv into MFMA image; zero zbuf.
// ============================================================================
__global__ __launch_bounds__(256) void k0_wprep(const float* __restrict__ wqkv,
                                                unsigned* __restrict__ wimg,
                                                float* __restrict__ zbuf) {
  int id = blockIdx.x * 256 + threadIdx.x;   // 0..24575
  if (id < 16) zbuf[id] = 0.f;
  int i = id & 3;
  int co = (id >> 2) & 127;
  int kgrp = (id >> 9) & 3;
  int c = (id >> 11) & 3;
  int m = id >> 13;
  int ci = c * 32 + kgrp * 8 + 2 * i;
  const float* wrow = wqkv + (size_t)(m * 128 + co) * 128 + ci;
  unsigned hi, lo;
  packpair(wrow[0], wrow[1], hi, lo);
  size_t base = (size_t)(m * 4 + c) * SEC + kgrp * KGP + co * 4 + i;
  wimg[base] = hi;
  wimg[base + PLN] = lo;
}

// ============================================================================
// K1: qkv = W @ X via split-bf16 MFMA (unchanged, proven)
// ============================================================================
__global__ __launch_bounds__(256) void k1_qkv_mfma(const float* __restrict__ x,
                                                   const unsigned* __restrict__ wimg,
                                                   float* __restrict__ qkv) {
  __shared__ __align__(16) unsigned Xp[4 * KGP];
  __shared__ __align__(16) unsigned Wp[4 * KGP];
  const int t = threadIdx.x;
  const int p = blockIdx.x;
  const int qd = p / 24;
  const int r_ = p - qd * 24;
  const int m = r_ >> 3;
  const int tt = qd * 8 + (r_ & 7);
  const int n0 = (tt & 127) * 128;
  const int b = tt >> 7;
  const float* xb = x + (size_t)b * CIN * NPIX + n0;

  const int l = t & 63;
  const int w = t >> 6;
  const int g = l >> 4;
  const int lc = l & 15;
  const int ch = w >> 1;
  const int nh = w & 1;
  const int kg = t >> 6;
  const int nn_ = t & 63;

  f32x4 acc[4][4];
  #pragma unroll
  for (int i = 0; i < 4; ++i)
    #pragma unroll
    for (int j = 0; j < 4; ++j) acc[i][j] = (f32x4){0.f, 0.f, 0.f, 0.f};

  for (int c = 0; c < 4; ++c) {
    {
      const uint4* wsrc = (const uint4*)(wimg + (size_t)(m * 4 + c) * SEC);
      uint4* wdst = (uint4*)Wp;
      #pragma unroll
      for (int r = 0; r < 5; ++r) {
        int idx = t + r * 256;
        if (idx < 1040) wdst[idx] = wsrc[idx];
      }
    }
    {
      const float* colbase = xb + (size_t)(c * 32 + kg * 8) * NPIX;
      #pragma unroll
      for (int half = 0; half < 2; ++half) {
        int n = nn_ + half * 64;
        const float* colp = colbase + n;
        unsigned hp[4], lp[4];
        #pragma unroll
        for (int i = 0; i < 4; ++i)
          packpair(colp[(size_t)(2 * i) * NPIX], colp[(size_t)(2 * i + 1) * NPIX],
                   hp[i], lp[i]);
        *(uint4*)&Xp[kg * KGP + n * 4] = make_uint4(hp[0], hp[1], hp[2], hp[3]);
        *(uint4*)&Xp[kg * KGP + PLN + n * 4] = make_uint4(lp[0], lp[1], lp[2], lp[3]);
      }
    }
    __syncthreads();

    bf16x8 bh[4], bl[4];
    #pragma unroll
    for (int ng = 0; ng < 4; ++ng) {
      const int nb = (nh * 64 + ng * 16 + lc) * 4;
      bh[ng] = *(const bf16x8*)&Xp[g * KGP + nb];
      bl[ng] = *(const bf16x8*)&Xp[g * KGP + PLN + nb];
    }
    #pragma unroll
    for (int cg = 0; cg < 4; ++cg) {
      const int cb = (ch * 64 + cg * 16 + lc) * 4;
      bf16x8 ah = *(const bf16x8*)&Wp[g * KGP + cb];
      bf16x8 al = *(const bf16x8*)&Wp[g * KGP + PLN + cb];
      #pragma unroll
      for (int ng = 0; ng < 4; ++ng) {
        acc[cg][ng] = __builtin_amdgcn_mfma_f32_16x16x32_bf16(ah, bh[ng], acc[cg][ng], 0, 0, 0);
        acc[cg][ng] = __builtin_amdgcn_mfma_f32_16x16x32_bf16(ah, bl[ng], acc[cg][ng], 0, 0, 0);
        acc[cg][ng] = __builtin_amdgcn_mfma_f32_16x16x32_bf16(al, bh[ng], acc[cg][ng], 0, 0, 0);
      }
    }
    __syncthreads();
  }
  #pragma unroll
  for (int cg = 0; cg < 4; ++cg) {
    const size_t corow = (size_t)b * T3 + m * 128 + ch * 64 + cg * 16 + g * 4;
    #pragma unroll
    for (int ng = 0; ng < 4; ++ng) {
      const int nn = n0 + nh * 64 + ng * 16 + lc;
      #pragma unroll
      for (int rr = 0; rr < 4; ++rr)
        qkv[(corow + rr) * NPIX + nn] = acc[cg][ng][rr];
    }
  }
}

// ============================================================================
// dw helpers: load (24 hoisted, OOB->zbuf) / math (identical op order to R8)
// ============================================================================
#define PDW 36

__device__ __forceinline__ void dw_load(const float* __restrict__ plane,
                                        const float* __restrict__ zbuf,
                                        int x0, int y0, int xq, int yg,
                                        f32x4 u[8][3]) {
  const int gx0 = x0 + 4 * xq - 4;
  const bool ex0 = (gx0 >= 0);
  const bool ex2 = (gx0 + 11 < WW);
  #pragma unroll
  for (int r = 0; r < 8; ++r) {
    const int gy = y0 + 4 * yg - 2 + r;
    const bool iny = (unsigned)gy < (unsigned)HH;
    const float* rp = plane + gy * WW + gx0;
    const float* p0 = (iny && ex0) ? rp : zbuf;
    const float* p1 = iny ? (rp + 4) : zbuf;
    const float* p2 = (iny && ex2) ? (rp + 8) : zbuf;
    u[r][0] = *(const f32x4*)p0;
    u[r][1] = *(const f32x4*)p1;
    u[r][2] = *(const f32x4*)p2;
  }
}

__device__ __forceinline__ void dw_math(const f32x4 u[8][3],
                                        const float* __restrict__ w25,
                                        float dacc[4][4]) {
  #pragma unroll
  for (int jy = 0; jy < 4; ++jy)
    #pragma unroll
    for (int jx = 0; jx < 4; ++jx) dacc[jy][jx] = 0.f;
  #pragma unroll
  for (int r = 0; r < 8; ++r) {
    float vals[12] = {u[r][0][0], u[r][0][1], u[r][0][2], u[r][0][3],
                      u[r][1][0], u[r][1][1], u[r][1][2], u[r][1][3],
                      u[r][2][0], u[r][2][1], u[r][2][2], u[r][2][3]};
    #pragma unroll
    for (int jy = 0; jy < 4; ++jy) {
      int ky = r - jy;
      if (ky < 0 || ky > 4) continue;
      #pragma unroll
      for (int kx = 0; kx < 5; ++kx) {
        float wv = w25[ky * 5 + kx];
        #pragma unroll
        for (int jx = 0; jx < 4; ++jx)
          dacc[jy][jx] += wv * vals[jx + kx + 2];
      }
    }
  }
}

// ============================================================================
// K2q: q~ groups only (g = 3h). R8's proven kernel, 1/3 grid.
// ============================================================================
__global__ __launch_bounds__(256, 2) void k2_q(const float* __restrict__ qkv,
                                               const float* __restrict__ wdw,
                                               const float* __restrict__ wpw,
                                               const float* __restrict__ zbuf,
                                               float* __restrict__ agg) {
  __shared__ __align__(16) float dws[8 * 16 * PDW];
  __shared__ float wds[8][25];
  __shared__ float wps[64];
  const int t = threadIdx.x;
  const int p = blockIdx.x;                 // 0..2047
  const int L = (p & 7) * 256 + (p >> 3);
  const int z = L >> 5;                     // b*16+hh
  const int rem = L & 31;
  const int x0 = (rem & 3) * 32;
  const int y0 = (rem >> 2) * 16;
  const int b = z >> 4;
  const int hh = z & 15;
  const float* src = qkv + ((size_t)b * T3 + hh * 24) * NPIX;

  for (int idx = t; idx < 200; idx += 256)
    wds[idx / 25][idx % 25] = wdw[(size_t)hh * 600 + idx];
  if (t < 64) wps[t] = wpw[hh * 192 + t];
  __syncthreads();

  const int ch = t >> 5;
  const int xq = t & 7;
  const int yg = (t >> 3) & 3;

  f32x4 u[8][3];
  dw_load(src + (size_t)ch * NPIX, zbuf, x0, y0, xq, yg, u);
  float dacc[4][4];
  dw_math(u, &wds[ch][0], dacc);

  #pragma unroll
  for (int jy = 0; jy < 4; ++jy) {
    float4 o = make_float4(dacc[jy][0], dacc[jy][1], dacc[jy][2], dacc[jy][3]);
    *(float4*)&dws[ch * (16 * PDW) + (yg * 4 + jy) * PDW + xq * 4] = o;
  }
  __syncthreads();

  float* dst = agg + ((size_t)b * T3 + hh * 24) * NPIX + (size_t)y0 * WW + x0;
  #pragma unroll
  for (int pp = 0; pp < 2; ++pp) {
    int pix = t + pp * 256;
    int py = pix >> 5;
    int px = pix & 31;
    float dv[8];
    #pragma unroll
    for (int ic = 0; ic < 8; ++ic) dv[ic] = dws[ic * (16 * PDW) + py * PDW + px];
    #pragma unroll
    for (int oc = 0; oc < 8; ++oc) {
      float s = 0.f;
      #pragma unroll
      for (int ic = 0; ic < 8; ++ic) s += wps[oc * 8 + ic] * dv[ic];
      dst[(size_t)oc * NPIX + py * WW + px] = s;
    }
  }
}

// ============================================================================
// vk wave reduce over 512 px (kb relu'd, vb) -> 72-float partial.
// ============================================================================
__device__ __forceinline__ void vk_reduce(const float* __restrict__ kb,
                                          const float* __restrict__ vb,
                                          float* __restrict__ pr, int t) {
  const int wv = t >> 6;
  const int lane = t & 63;
  const int d0 = wv * 2;
  float accA[8], accB[8], accS[8];
  #pragma unroll
  for (int e = 0; e < 8; ++e) { accA[e] = 0.f; accB[e] = 0.f; accS[e] = 0.f; }
  #pragma unroll
  for (int it = 0; it < 8; ++it) {
    int p = it * 64 + lane;
    float kv[8];
    #pragma unroll
    for (int e = 0; e < 8; ++e) kv[e] = kb[e * 512 + p];
    float vA = vb[d0 * 512 + p];
    float vB = vb[(d0 + 1) * 512 + p];
    #pragma unroll
    for (int e = 0; e < 8; ++e) { accA[e] += vA * kv[e]; accB[e] += vB * kv[e]; }
    if (wv == 0) {
      #pragma unroll
      for (int e = 0; e < 8; ++e) accS[e] += kv[e];
    }
  }
  #pragma unroll
  for (int e = 0; e < 8; ++e) {
    #pragma unroll
    for (int m = 1; m < 64; m <<= 1) {
      accA[e] += __shfl_xor(accA[e], m);
      accB[e] += __shfl_xor(accB[e], m);
    }
  }
  if (wv == 0) {
    #pragma unroll
    for (int e = 0; e < 8; ++e)
      #pragma unroll
      for (int m = 1; m < 64; m <<= 1) accS[e] += __shfl_xor(accS[e], m);
  }
  if (lane == 0) {
    #pragma unroll
    for (int e = 0; e < 8; ++e) {
      pr[d0 * 8 + e] = accA[e];
      pr[(d0 + 1) * 8 + e] = accB[e];
    }
    if (wv == 0) {
      #pragma unroll
      for (int e = 0; e < 8; ++e) pr[64 + e] = accS[e];
    }
  }
}

// ============================================================================
// K2kv: per (b, head, tile): dwK->pwK->kbuf(relu), dwV->pwV->vbuf,
// vkA (agg head), restage qkv k/v center, vkB (qkv head).
// k~/v~ NEVER written to HBM. 7 barriers; V-loads hoisted across pwK;
// restage loads hoisted across vkA. LDS 53 KB -> 3 blocks/CU.
// ============================================================================
__global__ __launch_bounds__(256, 2) void k2_kv(const float* __restrict__ qkv,
                                                const float* __restrict__ wdw,
                                                const float* __restrict__ wpw,
                                                const float* __restrict__ zbuf,
                                                float* __restrict__ part2) {
  __shared__ __align__(16) float buf1[8 * 16 * PDW];  // 4608: dw transpose
  __shared__ __align__(16) float kbuf[8 * 512];
  __shared__ __align__(16) float vbuf[8 * 512];
  __shared__ float wds[16][25];
  __shared__ float wps[128];
  const int t = threadIdx.x;
  const int p = blockIdx.x;                 // 0..2047
  const int L = (p & 7) * 256 + (p >> 3);
  const int z = L >> 5;                     // b*16+hh
  const int rem = L & 31;
  const int x0 = (rem & 3) * 32;
  const int y0 = (rem >> 2) * 16;
  const int b = z >> 4;
  const int hh = z & 15;
  const float* src = qkv + ((size_t)b * T3 + hh * 24) * NPIX;

  for (int idx = t; idx < 400; idx += 256)
    wds[idx / 25][idx % 25] = wdw[(size_t)hh * 600 + 200 + idx];
  if (t < 128) wps[t] = wpw[hh * 192 + 64 + t];
  __syncthreads();

  const int ch = t >> 5;
  const int xq = t & 7;
  const int yg = (t >> 3) & 3;

  // ---- dwK: load + math -> buf1 ----
  {
    f32x4 uK[8][3];
    dw_load(src + (size_t)(8 + ch) * NPIX, zbuf, x0, y0, xq, yg, uK);
    float dacc[4][4];
    dw_math(uK, &wds[ch][0], dacc);
    #pragma unroll
    for (int jy = 0; jy < 4; ++jy)
      *(float4*)&buf1[ch * (16 * PDW) + (yg * 4 + jy) * PDW + xq * 4] =
          make_float4(dacc[jy][0], dacc[jy][1], dacc[jy][2], dacc[jy][3]);
  }
  __syncthreads();

  // ---- issue V window loads (overlap pwK), then pwK -> kbuf(relu) ----
  f32x4 uV[8][3];
  dw_load(src + (size_t)(16 + ch) * NPIX, zbuf, x0, y0, xq, yg, uV);
  #pragma unroll
  for (int pp = 0; pp < 2; ++pp) {
    int pix = t + pp * 256;
    int py = pix >> 5, px = pix & 31;
    float dv[8];
    #pragma unroll
    for (int ic = 0; ic < 8; ++ic) dv[ic] = buf1[ic * (16 * PDW) + py * PDW + px];
    #pragma unroll
    for (int oc = 0; oc < 8; ++oc) {
      float s = 0.f;
      #pragma unroll
      for (int ic = 0; ic < 8; ++ic) s += wps[oc * 8 + ic] * dv[ic];
      kbuf[oc * 512 + pix] = fmaxf(s, 0.f);
    }
  }
  __syncthreads();   // buf1 reads done

  // ---- dwV math -> buf1 ----
  {
    float dacc[4][4];
    dw_math(uV, &wds[8 + ch][0], dacc);
    #pragma unroll
    for (int jy = 0; jy < 4; ++jy)
      *(float4*)&buf1[ch * (16 * PDW) + (yg * 4 + jy) * PDW + xq * 4] =
          make_float4(dacc[jy][0], dacc[jy][1], dacc[jy][2], dacc[jy][3]);
  }
  __syncthreads();

  // ---- pwV -> vbuf ----
  #pragma unroll
  for (int pp = 0; pp < 2; ++pp) {
    int pix = t + pp * 256;
    int py = pix >> 5, px = pix & 31;
    float dv[8];
    #pragma unroll
    for (int ic = 0; ic < 8; ++ic) dv[ic] = buf1[ic * (16 * PDW) + py * PDW + px];
    #pragma unroll
    for (int oc = 0; oc < 8; ++oc) {
      float s = 0.f;
      #pragma unroll
      for (int ic = 0; ic < 8; ++ic) s += wps[64 + oc * 8 + ic] * dv[ic];
      vbuf[oc * 512 + pix] = s;
    }
  }
  __syncthreads();   // kbuf+vbuf ready

  // ---- issue restage loads (fly across vkA), then vkA (agg head) ----
  f32x4 rs[8];
  #pragma unroll
  for (int j = 0; j < 8; ++j) {
    int qd2 = t + j * 256;
    int buf = qd2 >> 10;
    int ch2 = (qd2 >> 7) & 7;
    int r2 = qd2 & 127;
    int py = r2 >> 3, qx = r2 & 7;
    const float* gp = src + (size_t)(8 + buf * 8 + ch2) * NPIX + (y0 + py) * WW + x0 + qx * 4;
    rs[j] = *(const f32x4*)gp;
  }
  vk_reduce(kbuf, vbuf, part2 + ((size_t)(z * 2 + 1) * 32 + rem) * 72, t);
  __syncthreads();   // kbuf/vbuf reads done

  // ---- write restaged qkv k/v center rows ----
  #pragma unroll
  for (int j = 0; j < 8; ++j) {
    int qd2 = t + j * 256;
    int buf = qd2 >> 10;
    int ch2 = (qd2 >> 7) & 7;
    int r2 = qd2 & 127;
    int py = r2 >> 3, qx = r2 & 7;
    f32x4 v = rs[j];
    if (buf == 0) {
      v[0] = fmaxf(v[0], 0.f); v[1] = fmaxf(v[1], 0.f);
      v[2] = fmaxf(v[2], 0.f); v[3] = fmaxf(v[3], 0.f);
      *(f32x4*)&kbuf[ch2 * 512 + py * 32 + qx * 4] = v;
    } else {
      *(f32x4*)&vbuf[ch2 * 512 + py * 32 + qx * 4] = v;
    }
  }
  __syncthreads();

  // ---- vkB (qkv head) ----
  vk_reduce(kbuf, vbuf, part2 + ((size_t)(z * 2 + 0) * 32 + rem) * 72, t);
}

// ============================================================================
// K3b: vk[bh] = sum over 32 tile partials (R9-proven layout).
// ============================================================================
__global__ __launch_bounds__(128) void k3b_sum(const float* __restrict__ part2,
                                               float* __restrict__ vk) {
  const int bh = blockIdx.x;
  const int j = threadIdx.x;
  if (j < 72) {
    int b = bh >> 5, h = bh & 31;
    int z = b * 16 + (h & 15);
    int ph = h >> 4;
    const float* srcp = part2 + ((size_t)(z * 2 + ph) * 32) * 72 + j;
    float s = 0.f;
    #pragma unroll
    for (int c = 0; c < 32; ++c) s += srcp[(size_t)c * 72];
    vk[(size_t)bh * 72 + j] = s;
  }
}

// ============================================================================
// K3c: M' image + shift (unchanged)
// ============================================================================
__global__ __launch_bounds__(256) void k3c_M(const float* __restrict__ wproj,
                                             const float* __restrict__ vk,
                                             const float* __restrict__ gamma,
                                             const float* __restrict__ beta,
                                             const float* __restrict__ mean,
                                             const float* __restrict__ var,
                                             unsigned* __restrict__ Mimg,
                                             float* __restrict__ shiftb) {
  int id = blockIdx.x * 256 + threadIdx.x;
  int i = id & 3;
  int co = (id >> 2) & 127;
  int kgrp = (id >> 9) & 3;
  int cidx = (id >> 11) & 7;
  int b = id >> 14;
  int h = cidx * 4 + kgrp;
  float inv = gamma[co] * rsqrtf(var[co] + 1e-5f);
  const float* wrow = wproj + (size_t)co * 256 + h * 8;
  const float* vkc = vk + ((size_t)b * 32 + h) * 72;
  float s0 = 0.f, s1 = 0.f;
  #pragma unroll
  for (int d = 0; d < 8; ++d) {
    float wv = wrow[d];
    s0 += wv * vkc[d * 8 + 2 * i];
    s1 += wv * vkc[d * 8 + 2 * i + 1];
  }
  unsigned hi, lo;
  packpair(inv * s0, inv * s1, hi, lo);
  size_t base = (size_t)(b * 8 + cidx) * SEC + kgrp * KGP + co * 4 + i;
  Mimg[base] = hi;
  Mimg[base + PLN] = lo;
  if (b == 0 && cidx == 0 && kgrp == 0 && i == 0)
    shiftb[co] = beta[co] - mean[co] * inv;
}

// ============================================================================
// K4: out = M' @ Q' + shift via split-bf16 MFMA, 64-wide n-tiles (unchanged)
// ============================================================================
__global__ __launch_bounds__(256) void k4_mfma(const float* __restrict__ qkv,
                                               const float* __restrict__ agg,
                                               const float* __restrict__ vk,
                                               const unsigned* __restrict__ Mimg,
                                               const float* __restrict__ shiftb,
                                               float* __restrict__ out) {
  __shared__ __align__(16) unsigned Ap[4 * KGP];
  __shared__ __align__(16) unsigned Bp[4 * KGPB];
  const int t = threadIdx.x;
  const int n0 = blockIdx.x * 64;
  const int b = blockIdx.y;

  const int l = t & 63;
  const int w = t >> 6;
  const int g = l >> 4;
  const int lc = l & 15;
  const int ch = w >> 1;
  const int nh = w & 1;
  const int hj = t >> 6;
  const int nn_ = t & 63;

  f32x4 acc[4][2];
  #pragma unroll
  for (int i = 0; i < 4; ++i)
    #pragma unroll
    for (int j = 0; j < 2; ++j) acc[i][j] = (f32x4){0.f, 0.f, 0.f, 0.f};

  for (int cidx = 0; cidx < 8; ++cidx) {
    {
      const uint4* asrc = (const uint4*)(Mimg + (size_t)(b * 8 + cidx) * SEC);
      uint4* adst = (uint4*)Ap;
      #pragma unroll
      for (int r = 0; r < 5; ++r) {
        int idx = t + r * 256;
        if (idx < 1040) adst[idx] = asrc[idx];
      }
    }
    {
      const int h = cidx * 4 + hj;
      const float* srcb = (h < 16 ? qkv : agg) +
                          ((size_t)b * T3 + (h & 15) * 24) * NPIX + n0 + nn_;
      const float* vkr = vk + ((size_t)b * 32 + h) * 72 + 64;
      float q[8];
      float den = 1e-15f;
      #pragma unroll
      for (int e = 0; e < 8; ++e) {
        q[e] = fmaxf(srcb[(size_t)e * NPIX], 0.f);
        den += vkr[e] * q[e];
      }
      float rd = 1.0f / den;
      unsigned hp[4], lp[4];
      #pragma unroll
      for (int i = 0; i < 4; ++i)
        packpair(q[2 * i] * rd, q[2 * i + 1] * rd, hp[i], lp[i]);
      *(uint4*)&Bp[hj * KGPB + nn_ * 4] = make_uint4(hp[0], hp[1], hp[2], hp[3]);
      *(uint4*)&Bp[hj * KGPB + PLNB + nn_ * 4] = make_uint4(lp[0], lp[1], lp[2], lp[3]);
    }
    __syncthreads();

    bf16x8 bhf[2], blf[2];
    #pragma unroll
    for (int ng = 0; ng < 2; ++ng) {
      const int nb = (nh * 32 + ng * 16 + lc) * 4;
      bhf[ng] = *(const bf16x8*)&Bp[g * KGPB + nb];
      blf[ng] = *(const bf16x8*)&Bp[g * KGPB + PLNB + nb];
    }
    #pragma unroll
    for (int cg = 0; cg < 4; ++cg) {
      const int cb = (ch * 64 + cg * 16 + lc) * 4;
      bf16x8 ah = *(const bf16x8*)&Ap[g * KGP + cb];
      bf16x8 al = *(const bf16x8*)&Ap[g * KGP + PLN + cb];
      #pragma unroll
      for (int ng = 0; ng < 2; ++ng) {
        acc[cg][ng] = __builtin_amdgcn_mfma_f32_16x16x32_bf16(ah, bhf[ng], acc[cg][ng], 0, 0, 0);
        acc[cg][ng] = __builtin_amdgcn_mfma_f32_16x16x32_bf16(ah, blf[ng], acc[cg][ng], 0, 0, 0);
        acc[cg][ng] = __builtin_amdgcn_mfma_f32_16x16x32_bf16(al, bhf[ng], acc[cg][ng], 0, 0, 0);
      }
    }
    __syncthreads();
  }
  #pragma unroll
  for (int cg = 0; cg < 4; ++cg) {
    const int cobase = ch * 64 + cg * 16 + g * 4;
    #pragma unroll
    for (int ng = 0; ng < 2; ++ng) {
      const int nn = n0 + nh * 32 + ng * 16 + lc;
      #pragma unroll
      for (int rr = 0; rr < 4; ++rr) {
        int co = cobase + rr;
        out[((size_t)b * 128 + co) * NPIX + nn] = acc[cg][ng][rr] + shiftb[co];
      }
    }
  }
}

__global__ void fill_sentinel(float* o, int n) {
  int i = blockIdx.x * 256 + threadIdx.x;
  if (i < n) o[i] = 12345.0f;
}

extern "C" void kernel_launch(void* const* d_in, const int* in_sizes, int n_in,
                              void* d_out, int out_size, void* d_ws, size_t ws_size,
                              hipStream_t stream) {
  const float* x     = (const float*)d_in[0];
  const float* wqkv  = (const float*)d_in[1];
  const float* wdw   = (const float*)d_in[2];
  const float* wpw   = (const float*)d_in[3];
  const float* wproj = (const float*)d_in[4];
  const float* gamma = (const float*)d_in[5];
  const float* beta  = (const float*)d_in[6];
  const float* mean  = (const float*)d_in[7];
  const float* var   = (const float*)d_in[8];
  float* out = (float*)d_out;
  float* ws = (float*)d_ws;

  const size_t part2F = 64 * 2 * 32 * 72;        // 294912
  const size_t mimgF = 32 * SEC;                 // 133120
  const size_t wimgF = 12 * SEC;                 // 49920
  const size_t needF = (size_t)QKV_ELE * 2 + part2F + 9216 + 128 + mimgF + wimgF + 16;
  if (ws_size < needF * 4) {
    fill_sentinel<<<dim3((out_size + 255) / 256), dim3(256), 0, stream>>>(out, out_size);
    return;
  }
  float* qkv    = ws;
  float* agg    = qkv + QKV_ELE;
  float* part2  = agg + QKV_ELE;
  float* vkbuf  = part2 + part2F;
  float* shiftb = vkbuf + 9216;
  unsigned* Mimg = (unsigned*)(shiftb + 128);
  unsigned* wimg = Mimg + mimgF;
  float* zbuf   = (float*)(wimg + wimgF);

  k0_wprep<<<dim3(96), 256, 0, stream>>>(wqkv, wimg, zbuf);
  k1_qkv_mfma<<<dim3(1536), 256, 0, stream>>>(x, wimg, qkv);
  k2_q<<<dim3(2048), 256, 0, stream>>>(qkv, wdw, wpw, zbuf, agg);
  k2_kv<<<dim3(2048), 256, 0, stream>>>(qkv, wdw, wpw, zbuf, part2);
  k3b_sum<<<dim3(128), 128, 0, stream>>>(part2, vkbuf);
  k3c_M<<<dim3(256), 256, 0, stream>>>(wproj, vkbuf, gamma, beta, mean, var, Mimg, shiftb);
  k4_mfma<<<dim3(256, 4), 256, 0, stream>>>(qkv, agg, vkbuf, Mimg, shiftb, out);
}

// Round 13
// 134.727 us; speedup vs baseline: 1.1448x; 1.1448x over previous
//
#include <hip/hip_runtime.h>

#define BB 4
#define CIN 128
#define T3 384
#define HH 128
#define WW 128
#define NPIX 16384
#define QKV_ELE (BB*T3*NPIX)
#define NCHUNK 16

// MFMA packed-image geometry
#define SEC 4160
#define KGP 1040
#define PLN 520
// B tile (k4, 64-wide)
#define KGPB 520
#define PLNB 260

typedef __attribute__((ext_vector_type(8))) short bf16x8;
typedef __attribute__((ext_vector_type(4))) float f32x4;

__device__ __forceinline__ unsigned splitpack(float x) {
  unsigned u = __float_as_uint(x);
  unsigned hb = (u + 0x7fffu + ((u >> 16) & 1u)) >> 16;
  float lo = x - __uint_as_float(hb << 16);
  unsigned ul = __float_as_uint(lo);
  unsigned lb = (ul + 0x7fffu + ((ul >> 16) & 1u)) >> 16;
  return (hb << 16) | (lb & 0xffffu);
}

__device__ __forceinline__ void packpair(float a, float b, unsigned& hi, unsigned& lo) {
  unsigned p0 = splitpack(a), p1 = splitpack(b);
  hi = (p1 & 0xffff0000u) | (p0 >> 16);
  lo = (p1 << 16) | (p0 & 0xffffu);
}

// ============================================================================
// K0: pre-pack wqkv into MFMA image; zero zbuf.
// ============================================================================
__global__ __launch_bounds__(256) void k0_wprep(const float* __restrict__ wqkv,
                                                unsigned* __restrict__ wimg,
                                                float* __restrict__ zbuf) {
  int id = blockIdx.x * 256 + threadIdx.x;   // 0..24575
  if (id < 16) zbuf[id] = 0.f;
  int i = id & 3;
  int co = (id >> 2) & 127;
  int kgrp = (id >> 9) & 3;
  int c = (id >> 11) & 3;
  int m = id >> 13;
  int ci = c * 32 + kgrp * 8 + 2 * i;
  const float* wrow = wqkv + (size_t)(m * 128 + co) * 128 + ci;
  unsigned hi, lo;
  packpair(wrow[0], wrow[1], hi, lo);
  size_t base = (size_t)(m * 4 + c) * SEC + kgrp * KGP + co * 4 + i;
  wimg[base] = hi;
  wimg[base + PLN] = lo;
}

// ============================================================================
// K1: qkv = W @ X via split-bf16 MFMA, SOFTWARE-PIPELINED: chunk c+1's W/X
// loads issued right after the stage barrier -> retire under c's MFMAs.
// Math bit-identical to R11.
// ============================================================================
__global__ __launch_bounds__(256) void k1_qkv_mfma(const float* __restrict__ x,
                                                   const unsigned* __restrict__ wimg,
                                                   float* __restrict__ qkv) {
  __shared__ __align__(16) unsigned Xp[4 * KGP];
  __shared__ __align__(16) unsigned Wp[4 * KGP];
  const int t = threadIdx.x;
  const int p = blockIdx.x;
  const int qd = p / 24;
  const int r_ = p - qd * 24;
  const int m = r_ >> 3;
  const int tt = qd * 8 + (r_ & 7);
  const int n0 = (tt & 127) * 128;
  const int b = tt >> 7;
  const float* xb = x + (size_t)b * CIN * NPIX + n0;

  const int l = t & 63;
  const int w = t >> 6;
  const int g = l >> 4;
  const int lc = l & 15;
  const int ch = w >> 1;
  const int nh = w & 1;
  const int kg = t >> 6;
  const int nn_ = t & 63;

  f32x4 acc[4][4];
  #pragma unroll
  for (int i = 0; i < 4; ++i)
    #pragma unroll
    for (int j = 0; j < 4; ++j) acc[i][j] = (f32x4){0.f, 0.f, 0.f, 0.f};

  uint4 wpre[5];
  float xpre[16];

  // preload chunk 0
  {
    const uint4* wsrc = (const uint4*)(wimg + (size_t)(m * 4 + 0) * SEC);
    #pragma unroll
    for (int r = 0; r < 5; ++r) {
      int idx = t + r * 256;
      uint4 v = make_uint4(0u, 0u, 0u, 0u);
      if (idx < 1040) v = wsrc[idx];
      wpre[r] = v;
    }
    const float* colbase = xb + (size_t)(kg * 8) * NPIX;
    #pragma unroll
    for (int half = 0; half < 2; ++half) {
      const float* colp = colbase + nn_ + half * 64;
      #pragma unroll
      for (int i = 0; i < 8; ++i)
        xpre[half * 8 + i] = colp[(size_t)i * NPIX];
    }
  }

  for (int c = 0; c < 4; ++c) {
    {  // stage from preloaded registers
      uint4* wdst = (uint4*)Wp;
      #pragma unroll
      for (int r = 0; r < 5; ++r) {
        int idx = t + r * 256;
        if (idx < 1040) wdst[idx] = wpre[r];
      }
      #pragma unroll
      for (int half = 0; half < 2; ++half) {
        int n = nn_ + half * 64;
        unsigned hp[4], lp[4];
        #pragma unroll
        for (int i = 0; i < 4; ++i)
          packpair(xpre[half * 8 + 2 * i], xpre[half * 8 + 2 * i + 1], hp[i], lp[i]);
        *(uint4*)&Xp[kg * KGP + n * 4] = make_uint4(hp[0], hp[1], hp[2], hp[3]);
        *(uint4*)&Xp[kg * KGP + PLN + n * 4] = make_uint4(lp[0], lp[1], lp[2], lp[3]);
      }
    }
    __syncthreads();

    if (c < 3) {  // issue chunk c+1 loads; they retire under the MFMAs below
      const uint4* wsrc = (const uint4*)(wimg + (size_t)(m * 4 + c + 1) * SEC);
      #pragma unroll
      for (int r = 0; r < 5; ++r) {
        int idx = t + r * 256;
        uint4 v = make_uint4(0u, 0u, 0u, 0u);
        if (idx < 1040) v = wsrc[idx];
        wpre[r] = v;
      }
      const float* colbase = xb + (size_t)((c + 1) * 32 + kg * 8) * NPIX;
      #pragma unroll
      for (int half = 0; half < 2; ++half) {
        const float* colp = colbase + nn_ + half * 64;
        #pragma unroll
        for (int i = 0; i < 8; ++i)
          xpre[half * 8 + i] = colp[(size_t)i * NPIX];
      }
    }

    bf16x8 bh[4], bl[4];
    #pragma unroll
    for (int ng = 0; ng < 4; ++ng) {
      const int nb = (nh * 64 + ng * 16 + lc) * 4;
      bh[ng] = *(const bf16x8*)&Xp[g * KGP + nb];
      bl[ng] = *(const bf16x8*)&Xp[g * KGP + PLN + nb];
    }
    #pragma unroll
    for (int cg = 0; cg < 4; ++cg) {
      const int cb = (ch * 64 + cg * 16 + lc) * 4;
      bf16x8 ah = *(const bf16x8*)&Wp[g * KGP + cb];
      bf16x8 al = *(const bf16x8*)&Wp[g * KGP + PLN + cb];
      #pragma unroll
      for (int ng = 0; ng < 4; ++ng) {
        acc[cg][ng] = __builtin_amdgcn_mfma_f32_16x16x32_bf16(ah, bh[ng], acc[cg][ng], 0, 0, 0);
        acc[cg][ng] = __builtin_amdgcn_mfma_f32_16x16x32_bf16(ah, bl[ng], acc[cg][ng], 0, 0, 0);
        acc[cg][ng] = __builtin_amdgcn_mfma_f32_16x16x32_bf16(al, bh[ng], acc[cg][ng], 0, 0, 0);
      }
    }
    __syncthreads();
  }
  #pragma unroll
  for (int cg = 0; cg < 4; ++cg) {
    const size_t corow = (size_t)b * T3 + m * 128 + ch * 64 + cg * 16 + g * 4;
    #pragma unroll
    for (int ng = 0; ng < 4; ++ng) {
      const int nn = n0 + nh * 64 + ng * 16 + lc;
      #pragma unroll
      for (int rr = 0; rr < 4; ++rr)
        qkv[(corow + rr) * NPIX + nn] = acc[cg][ng][rr];
    }
  }
}

// ============================================================================
// K2: agg = grouped_pw( dw5x5(qkv) ). R11-proven (47.6 µs).
// ============================================================================
#define PDW 36
__global__ __launch_bounds__(256, 2) void k2_dwpw(const float* __restrict__ qkv,
                                                  const float* __restrict__ wdw,
                                                  const float* __restrict__ wpw,
                                                  const float* __restrict__ zbuf,
                                                  float* __restrict__ agg) {
  __shared__ __align__(16) float dws[8 * 16 * PDW];
  __shared__ float wds[8][25];
  __shared__ float wps[64];
  const int t = threadIdx.x;
  const int p = blockIdx.x;                 // 0..6143
  const int L = (p & 7) * 768 + (p >> 3);
  const int z = L >> 5;
  const int rem = L & 31;
  const int x0 = (rem & 3) * 32;
  const int y0 = (rem >> 2) * 16;
  const int b = z / 48;
  const int g = z % 48;
  const float* src = qkv + ((size_t)b * T3 + g * 8) * NPIX;

  for (int idx = t; idx < 200; idx += 256)
    wds[idx / 25][idx % 25] = wdw[(size_t)g * 200 + idx];
  if (t < 64) wps[t] = wpw[g * 64 + t];
  __syncthreads();

  const int ch = t >> 5;
  const int xq = t & 7;
  const int yg = (t >> 3) & 3;
  const float* plane = src + (size_t)ch * NPIX;
  const int gx0 = x0 + 4 * xq - 4;
  const bool ex0 = (gx0 >= 0);
  const bool ex2 = (gx0 + 11 < WW);

  f32x4 u[8][3];
  #pragma unroll
  for (int r = 0; r < 8; ++r) {
    const int gy = y0 + 4 * yg - 2 + r;
    const bool iny = (unsigned)gy < (unsigned)HH;
    const float* rp = plane + gy * WW + gx0;
    const float* p0 = (iny && ex0) ? rp : zbuf;
    const float* p1 = iny ? (rp + 4) : zbuf;
    const float* p2 = (iny && ex2) ? (rp + 8) : zbuf;
    u[r][0] = *(const f32x4*)p0;
    u[r][1] = *(const f32x4*)p1;
    u[r][2] = *(const f32x4*)p2;
  }

  float dacc[4][4];
  #pragma unroll
  for (int jy = 0; jy < 4; ++jy)
    #pragma unroll
    for (int jx = 0; jx < 4; ++jx) dacc[jy][jx] = 0.f;

  #pragma unroll
  for (int r = 0; r < 8; ++r) {
    float vals[12] = {u[r][0][0], u[r][0][1], u[r][0][2], u[r][0][3],
                      u[r][1][0], u[r][1][1], u[r][1][2], u[r][1][3],
                      u[r][2][0], u[r][2][1], u[r][2][2], u[r][2][3]};
    #pragma unroll
    for (int jy = 0; jy < 4; ++jy) {
      int ky = r - jy;
      if (ky < 0 || ky > 4) continue;
      #pragma unroll
      for (int kx = 0; kx < 5; ++kx) {
        float wv = wds[ch][ky * 5 + kx];
        #pragma unroll
        for (int jx = 0; jx < 4; ++jx)
          dacc[jy][jx] += wv * vals[jx + kx + 2];
      }
    }
  }

  #pragma unroll
  for (int jy = 0; jy < 4; ++jy) {
    float4 o = make_float4(dacc[jy][0], dacc[jy][1], dacc[jy][2], dacc[jy][3]);
    *(float4*)&dws[ch * (16 * PDW) + (yg * 4 + jy) * PDW + xq * 4] = o;
  }
  __syncthreads();

  float* dst = agg + ((size_t)b * T3 + g * 8) * NPIX + (size_t)y0 * WW + x0;
  #pragma unroll
  for (int pp = 0; pp < 2; ++pp) {
    int pix = t + pp * 256;
    int py = pix >> 5;
    int px = pix & 31;
    float dv[8];
    #pragma unroll
    for (int ic = 0; ic < 8; ++ic) dv[ic] = dws[ic * (16 * PDW) + py * PDW + px];
    #pragma unroll
    for (int oc = 0; oc < 8; ++oc) {
      float s = 0.f;
      #pragma unroll
      for (int ic = 0; ic < 8; ++ic) s += wps[oc * 8 + ic] * dv[ic];
      dst[(size_t)oc * NPIX + py * WW + px] = s;
    }
  }
}

// ============================================================================
// K3: vk partials (R11-proven, at read roofline), k3b sum
// ============================================================================
__global__ __launch_bounds__(256) void k3_vk(const float* __restrict__ qkv,
                                             const float* __restrict__ agg,
                                             float* __restrict__ part) {
  const int chunk = blockIdx.x;
  const int bh = blockIdx.y;
  const int b = bh >> 5;
  const int h = bh & 31;
  const int hh = h & 15;
  const float* base = (h < 16 ? qkv : agg) + ((size_t)b * T3 + hh * 24) * NPIX;
  const float* kb = base + 8 * NPIX;
  const float* vb = base + 16 * NPIX;
  const int t = threadIdx.x;
  const int wv = t >> 6;
  const int lane = t & 63;
  const int d0 = wv * 2;

  float accA[8], accB[8], accS[8];
  #pragma unroll
  for (int e = 0; e < 8; ++e) { accA[e] = 0.f; accB[e] = 0.f; accS[e] = 0.f; }

  int p = chunk * (NPIX / NCHUNK) + lane;
  for (int it = 0; it < (NPIX / NCHUNK / 64); ++it, p += 64) {
    float kvv[8];
    #pragma unroll
    for (int e = 0; e < 8; ++e) kvv[e] = fmaxf(kb[(size_t)e * NPIX + p], 0.f);
    float vA = vb[(size_t)d0 * NPIX + p];
    float vB = vb[(size_t)(d0 + 1) * NPIX + p];
    #pragma unroll
    for (int e = 0; e < 8; ++e) { accA[e] += vA * kvv[e]; accB[e] += vB * kvv[e]; }
    if (wv == 0) {
      #pragma unroll
      for (int e = 0; e < 8; ++e) accS[e] += kvv[e];
    }
  }
  #pragma unroll
  for (int e = 0; e < 8; ++e) {
    #pragma unroll
    for (int m = 1; m < 64; m <<= 1) {
      accA[e] += __shfl_xor(accA[e], m);
      accB[e] += __shfl_xor(accB[e], m);
    }
  }
  if (wv == 0) {
    #pragma unroll
    for (int e = 0; e < 8; ++e)
      #pragma unroll
      for (int m = 1; m < 64; m <<= 1) accS[e] += __shfl_xor(accS[e], m);
  }
  if (lane == 0) {
    float* pr = part + ((size_t)bh * NCHUNK + chunk) * 72;
    #pragma unroll
    for (int e = 0; e < 8; ++e) {
      pr[d0 * 8 + e] = accA[e];
      pr[(d0 + 1) * 8 + e] = accB[e];
    }
    if (wv == 0) {
      #pragma unroll
      for (int e = 0; e < 8; ++e) pr[64 + e] = accS[e];
    }
  }
}

__global__ __launch_bounds__(128) void k3b_sum(const float* __restrict__ part,
                                               float* __restrict__ vk) {
  const int bh = blockIdx.x;
  const int j = threadIdx.x;
  if (j < 72) {
    float s = 0.f;
    #pragma unroll
    for (int c = 0; c < NCHUNK; ++c) s += part[((size_t)bh * NCHUNK + c) * 72 + j];
    vk[(size_t)bh * 72 + j] = s;
  }
}

// ============================================================================
// K3c: M' image + shift (unchanged)
// ============================================================================
__global__ __launch_bounds__(256) void k3c_M(const float* __restrict__ wproj,
                                             const float* __restrict__ vk,
                                             const float* __restrict__ gamma,
                                             const float* __restrict__ beta,
                                             const float* __restrict__ mean,
                                             const float* __restrict__ var,
                                             unsigned* __restrict__ Mimg,
                                             float* __restrict__ shiftb) {
  int id = blockIdx.x * 256 + threadIdx.x;
  int i = id & 3;
  int co = (id >> 2) & 127;
  int kgrp = (id >> 9) & 3;
  int cidx = (id >> 11) & 7;
  int b = id >> 14;
  int h = cidx * 4 + kgrp;
  float inv = gamma[co] * rsqrtf(var[co] + 1e-5f);
  const float* wrow = wproj + (size_t)co * 256 + h * 8;
  const float* vkc = vk + ((size_t)b * 32 + h) * 72;
  float s0 = 0.f, s1 = 0.f;
  #pragma unroll
  for (int d = 0; d < 8; ++d) {
    float wv = wrow[d];
    s0 += wv * vkc[d * 8 + 2 * i];
    s1 += wv * vkc[d * 8 + 2 * i + 1];
  }
  unsigned hi, lo;
  packpair(inv * s0, inv * s1, hi, lo);
  size_t base = (size_t)(b * 8 + cidx) * SEC + kgrp * KGP + co * 4 + i;
  Mimg[base] = hi;
  Mimg[base + PLN] = lo;
  if (b == 0 && cidx == 0 && kgrp == 0 && i == 0)
    shiftb[co] = beta[co] - mean[co] * inv;
}

// ============================================================================
// K4: out = M' @ Q' + shift, 64-wide n-tiles, SOFTWARE-PIPELINED: cidx+1's
// A-image uint4s + Q columns + vk row preloaded into registers right after
// the stage barrier. Math bit-identical to R11.
// ============================================================================
__global__ __launch_bounds__(256) void k4_mfma(const float* __restrict__ qkv,
                                               const float* __restrict__ agg,
                                               const float* __restrict__ vk,
                                               const unsigned* __restrict__ Mimg,
                                               const float* __restrict__ shiftb,
                                               float* __restrict__ out) {
  __shared__ __align__(16) unsigned Ap[4 * KGP];
  __shared__ __align__(16) unsigned Bp[4 * KGPB];
  const int t = threadIdx.x;
  const int n0 = blockIdx.x * 64;
  const int b = blockIdx.y;

  const int l = t & 63;
  const int w = t >> 6;
  const int g = l >> 4;
  const int lc = l & 15;
  const int ch = w >> 1;
  const int nh = w & 1;
  const int hj = t >> 6;
  const int nn_ = t & 63;

  f32x4 acc[4][2];
  #pragma unroll
  for (int i = 0; i < 4; ++i)
    #pragma unroll
    for (int j = 0; j < 2; ++j) acc[i][j] = (f32x4){0.f, 0.f, 0.f, 0.f};

  uint4 apre[5];
  float qpre[8];
  float vv[8];

  // preload cidx 0
  {
    const uint4* asrc = (const uint4*)(Mimg + (size_t)(b * 8 + 0) * SEC);
    #pragma unroll
    for (int r = 0; r < 5; ++r) {
      int idx = t + r * 256;
      uint4 v = make_uint4(0u, 0u, 0u, 0u);
      if (idx < 1040) v = asrc[idx];
      apre[r] = v;
    }
    const int h = hj;
    const float* srcb = (h < 16 ? qkv : agg) +
                        ((size_t)b * T3 + (h & 15) * 24) * NPIX + n0 + nn_;
    const float* vkr = vk + ((size_t)b * 32 + h) * 72 + 64;
    #pragma unroll
    for (int e = 0; e < 8; ++e) {
      qpre[e] = srcb[(size_t)e * NPIX];
      vv[e] = vkr[e];
    }
  }

  for (int cidx = 0; cidx < 8; ++cidx) {
    {  // stage A from regs
      uint4* adst = (uint4*)Ap;
      #pragma unroll
      for (int r = 0; r < 5; ++r) {
        int idx = t + r * 256;
        if (idx < 1040) adst[idx] = apre[r];
      }
    }
    {  // stage B from regs: relu, den, rescale, pack
      float q[8];
      float den = 1e-15f;
      #pragma unroll
      for (int e = 0; e < 8; ++e) {
        q[e] = fmaxf(qpre[e], 0.f);
        den += vv[e] * q[e];
      }
      float rd = 1.0f / den;
      unsigned hp[4], lp[4];
      #pragma unroll
      for (int i = 0; i < 4; ++i)
        packpair(q[2 * i] * rd, q[2 * i + 1] * rd, hp[i], lp[i]);
      *(uint4*)&Bp[hj * KGPB + nn_ * 4] = make_uint4(hp[0], hp[1], hp[2], hp[3]);
      *(uint4*)&Bp[hj * KGPB + PLNB + nn_ * 4] = make_uint4(lp[0], lp[1], lp[2], lp[3]);
    }
    __syncthreads();

    if (cidx < 7) {  // issue cidx+1 loads; retire under the MFMAs below
      const uint4* asrc = (const uint4*)(Mimg + (size_t)(b * 8 + cidx + 1) * SEC);
      #pragma unroll
      for (int r = 0; r < 5; ++r) {
        int idx = t + r * 256;
        uint4 v = make_uint4(0u, 0u, 0u, 0u);
        if (idx < 1040) v = asrc[idx];
        apre[r] = v;
      }
      const int h = (cidx + 1) * 4 + hj;
      const float* srcb = (h < 16 ? qkv : agg) +
                          ((size_t)b * T3 + (h & 15) * 24) * NPIX + n0 + nn_;
      const float* vkr = vk + ((size_t)b * 32 + h) * 72 + 64;
      #pragma unroll
      for (int e = 0; e < 8; ++e) {
        qpre[e] = srcb[(size_t)e * NPIX];
        vv[e] = vkr[e];
      }
    }

    bf16x8 bhf[2], blf[2];
    #pragma unroll
    for (int ng = 0; ng < 2; ++ng) {
      const int nb = (nh * 32 + ng * 16 + lc) * 4;
      bhf[ng] = *(const bf16x8*)&Bp[g * KGPB + nb];
      blf[ng] = *(const bf16x8*)&Bp[g * KGPB + PLNB + nb];
    }
    #pragma unroll
    for (int cg = 0; cg < 4; ++cg) {
      const int cb = (ch * 64 + cg * 16 + lc) * 4;
      bf16x8 ah = *(const bf16x8*)&Ap[g * KGP + cb];
      bf16x8 al = *(const bf16x8*)&Ap[g * KGP + PLN + cb];
      #pragma unroll
      for (int ng = 0; ng < 2; ++ng) {
        acc[cg][ng] = __builtin_amdgcn_mfma_f32_16x16x32_bf16(ah, bhf[ng], acc[cg][ng], 0, 0, 0);
        acc[cg][ng] = __builtin_amdgcn_mfma_f32_16x16x32_bf16(ah, blf[ng], acc[cg][ng], 0, 0, 0);
        acc[cg][ng] = __builtin_amdgcn_mfma_f32_16x16x32_bf16(al, bhf[ng], acc[cg][ng], 0, 0, 0);
      }
    }
    __syncthreads();
  }
  #pragma unroll
  for (int cg = 0; cg < 4; ++cg) {
    const int cobase = ch * 64 + cg * 16 + g * 4;
    #pragma unroll
    for (int ng = 0; ng < 2; ++ng) {
      const int nn = n0 + nh * 32 + ng * 16 + lc;
      #pragma unroll
      for (int rr = 0; rr < 4; ++rr) {
        int co = cobase + rr;
        out[((size_t)b * 128 + co) * NPIX + nn] = acc[cg][ng][rr] + shiftb[co];
      }
    }
  }
}

__global__ void fill_sentinel(float* o, int n) {
  int i = blockIdx.x * 256 + threadIdx.x;
  if (i < n) o[i] = 12345.0f;
}

extern "C" void kernel_launch(void* const* d_in, const int* in_sizes, int n_in,
                              void* d_out, int out_size, void* d_ws, size_t ws_size,
                              hipStream_t stream) {
  const float* x     = (const float*)d_in[0];
  const float* wqkv  = (const float*)d_in[1];
  const float* wdw   = (const float*)d_in[2];
  const float* wpw   = (const float*)d_in[3];
  const float* wproj = (const float*)d_in[4];
  const float* gamma = (const float*)d_in[5];
  const float* beta  = (const float*)d_in[6];
  const float* mean  = (const float*)d_in[7];
  const float* var   = (const float*)d_in[8];
  float* out = (float*)d_out;
  float* ws = (float*)d_ws;

  const size_t partF = 128 * NCHUNK * 72;        // 147456
  const size_t mimgF = 32 * SEC;                 // 133120
  const size_t wimgF = 12 * SEC;                 // 49920
  const size_t needF = (size_t)QKV_ELE * 2 + partF + 9216 + 128 + mimgF + wimgF + 16;
  if (ws_size < needF * 4) {
    fill_sentinel<<<dim3((out_size + 255) / 256), dim3(256), 0, stream>>>(out, out_size);
    return;
  }
  float* qkv    = ws;
  float* agg    = qkv + QKV_ELE;
  float* part   = agg + QKV_ELE;
  float* vkbuf  = part + partF;
  float* shiftb = vkbuf + 9216;
  unsigned* Mimg = (unsigned*)(shiftb + 128);
  unsigned* wimg = Mimg + mimgF;
  float* zbuf   = (float*)(wimg + wimgF);

  k0_wprep<<<dim3(96), 256, 0, stream>>>(wqkv, wimg, zbuf);
  k1_qkv_mfma<<<dim3(1536), 256, 0, stream>>>(x, wimg, qkv);
  k2_dwpw<<<dim3(6144), 256, 0, stream>>>(qkv, wdw, wpw, zbuf, agg);
  k3_vk<<<dim3(NCHUNK, 128), 256, 0, stream>>>(qkv, agg, part);
  k3b_sum<<<dim3(128), 128, 0, stream>>>(part, vkbuf);
  k3c_M<<<dim3(256), 256, 0, stream>>>(wproj, vkbuf, gamma, beta, mean, var, Mimg, shiftb);
  k4_mfma<<<dim3(256, 4), 256, 0, stream>>>(qkv, agg, vkbuf, Mimg, shiftb, out);
}